// Round 10
// baseline (298.054 us; speedup 1.0000x reference)
//
#include <hip/hip_runtime.h>
#include <math.h>

#define BB 1024
#define NN 512
#define MM 256
#define OUTROW (NN + MM + NN * MM)   // 131840
#define EPS_ADD 1e-16f
#define EPS_COS 1e-8f
#define G_REG 11                     // register-resident groups per wave (44 rows)
#define G_STREAM 21                  // streaming groups per wave (84 rows)
#define G_TOT 32                     // total 4-row groups per wave (128 rows)

typedef float f4v __attribute__((ext_vector_type(4)));

__device__ inline float waveReduceSum(float v) {
#pragma unroll
    for (int off = 32; off > 0; off >>= 1) v += __shfl_xor(v, off);
    return v;
}

__device__ __forceinline__ void ldgrp(f4v (&buf)[4], const float* __restrict__ rp) {
#pragma unroll
    for (int mc = 0; mc < 4; ++mc)
        buf[mc] = *reinterpret_cast<const f4v*>(rp + mc * 64);
}
__device__ __forceinline__ void ldgrp_nt(f4v (&buf)[4], const float* __restrict__ rp) {
#pragma unroll
    for (int mc = 0; mc < 4; ++mc)
        buf[mc] = __builtin_nontemporal_load(reinterpret_cast<const f4v*>(rp + mc * 64));
}

__device__ __forceinline__ void redgrp(const f4v (&buf)[4], const f4v (&kf)[4],
                                       float bet, float kn, float* __restrict__ sc,
                                       int row, int sl) {
    float dot = 0.f, ssq = 0.f;
#pragma unroll
    for (int mc = 0; mc < 4; ++mc) {
        const float mx = buf[mc].x + EPS_ADD, my = buf[mc].y + EPS_ADD;
        const float mz = buf[mc].z + EPS_ADD, mw = buf[mc].w + EPS_ADD;
        dot += mx * kf[mc].x + my * kf[mc].y + mz * kf[mc].z + mw * kf[mc].w;
        ssq += mx * mx + my * my + mz * mz + mw * mw;
    }
#pragma unroll
    for (int off = 8; off > 0; off >>= 1) {
        dot += __shfl_xor(dot, off);
        ssq += __shfl_xor(ssq, off);
    }
    if (sl == 0)
        sc[row] = bet * dot / (fmaxf(sqrtf(ssq), EPS_COS) * kn);
}

__device__ __forceinline__ void procgrp(const f4v (&mvv)[4], float wn,
                                        const f4v (&ev)[4], const f4v (&av)[4],
                                        f4v (&acc)[4], float* __restrict__ op) {
#pragma unroll
    for (int mc = 0; mc < 4; ++mc) {
        const f4v nm = mvv[mc] * (1.f - wn * ev[mc]) + wn * av[mc];
        __builtin_nontemporal_store(nm, reinterpret_cast<f4v*>(op + mc * 64));
        acc[mc] += wn * mvv[mc];
    }
}

__global__ __launch_bounds__(256, 2) void ntm_memory_kernel(
    const float* __restrict__ memory, const float* __restrict__ key,
    const float* __restrict__ beta, const float* __restrict__ g,
    const float* __restrict__ s, const float* __restrict__ gamma,
    const float* __restrict__ w_prev, const float* __restrict__ e,
    const float* __restrict__ a, float* __restrict__ out) {
    const int b    = blockIdx.x;
    const int t    = threadIdx.x;     // 0..255
    const int lane = t & 63;
    const int wave = t >> 6;          // 0..3
    const int sub  = lane >> 4;       // 0..3  row within group
    const int sl   = lane & 15;       // 0..15 lanes per row

    __shared__ float key_lds[MM];
    __shared__ float sc[NN];
    __shared__ float wg[NN];
    __shared__ float wf[NN];
    __shared__ float ea_lds[2 * MM];
    __shared__ float red[4];
    __shared__ float rpart[4][MM];

    const float* __restrict__ memb = memory + (size_t)b * NN * MM;
    float* __restrict__ outb       = out + (size_t)b * OUTROW;

    // ---- stage key (+eps), e, a ----
    key_lds[t]     = key[b * MM + t] + EPS_ADD;
    ea_lds[t]      = e[b * MM + t];
    ea_lds[MM + t] = a[b * MM + t];
    __syncthreads();

    // ---- key norm ----
    {
        const float kv = key_lds[t];
        const float ss = waveReduceSum(kv * kv);
        if (lane == 0) red[wave] = ss;
    }
    __syncthreads();
    const float kn  = fmaxf(sqrtf(red[0] + red[1] + red[2] + red[3]), EPS_COS);
    const float bet = beta[b];
    const float gv  = g[b];
    const float gam = gamma[b];
    const float s0  = s[b * 3 + 0];
    const float s1  = s[b * 3 + 1];
    const float s2  = s[b * 3 + 2];
    // (red is next written only after the post-phase-1 barrier — safe)

    const int rowbase = wave * 128 + sub;         // row of group gp = rowbase + 4*gp
    const float* __restrict__ rp0 = memb + (size_t)rowbase * MM + sl * 4;

    f4v kf[4];
#pragma unroll
    for (int mc = 0; mc < 4; ++mc)
        kf[mc] = *reinterpret_cast<const f4v*>(&key_lds[mc * 64 + sl * 4]);

    // ---- phase 1a: register tile (44 live-out NT loads => deep MLP) ----
    f4v tile[G_REG][4];
#pragma unroll
    for (int gp = 0; gp < G_REG; ++gp)
        ldgrp_nt(tile[gp], rp0 + (size_t)(4 * gp) * MM);

#pragma unroll
    for (int gp = 0; gp < G_REG; ++gp)
        redgrp(tile[gp], kf, bet, kn, sc, rowbase + 4 * gp, sl);

    // ---- phase 1b: 21 streaming groups, 2-deep ping-pong, cacheable ----
    {
        f4v s0b[4], s1b[4];
        ldgrp(s0b, rp0 + (size_t)(4 * (G_REG + 0)) * MM);
        ldgrp(s1b, rp0 + (size_t)(4 * (G_REG + 1)) * MM);
#pragma unroll
        for (int j = 0; j < G_STREAM; ++j) {
            if ((j & 1) == 0) {
                redgrp(s0b, kf, bet, kn, sc, rowbase + 4 * (G_REG + j), sl);
                if (j + 2 < G_STREAM)
                    ldgrp(s0b, rp0 + (size_t)(4 * (G_REG + j + 2)) * MM);
            } else {
                redgrp(s1b, kf, bet, kn, sc, rowbase + 4 * (G_REG + j), sl);
                if (j + 2 < G_STREAM)
                    ldgrp(s1b, rp0 + (size_t)(4 * (G_REG + j + 2)) * MM);
            }
        }
    }
    __syncthreads();

    // ---- softmax over N=512, 2 elems/thread, NO max pass (scores in [-1,1]) ----
    const float v0 = sc[t], v1 = sc[t + 256];
    const float ex0 = __expf(v0), ex1 = __expf(v1);
    {
        const float s1w = waveReduceSum(ex0 + ex1);
        if (lane == 0) red[wave] = s1w;
    }
    __syncthreads();
    const float esum = red[0] + red[1] + red[2] + red[3];

    // ---- gate + circular conv + sharpen ----
    wg[t]       = gv * (ex0 / esum) + (1.f - gv) * w_prev[b * NN + t];
    wg[t + 256] = gv * (ex1 / esum) + (1.f - gv) * w_prev[b * NN + t + 256];
    __syncthreads();
    const float wt0 = wg[(t + NN - 1) & (NN - 1)] * s0 + wg[t] * s1 +
                      wg[(t + 1) & (NN - 1)] * s2;
    const float wt1 = wg[(t + 255) & (NN - 1)] * s0 + wg[t + 256] * s1 +
                      wg[(t + 257) & (NN - 1)] * s2;
    const float wp0 = __powf(wt0, gam), wp1 = __powf(wt1, gam);
    {
        const float sw = waveReduceSum(wp0 + wp1);
        if (lane == 0) red[wave] = sw;
    }
    __syncthreads();
    const float wsum = red[0] + red[1] + red[2] + red[3] + EPS_ADD;
    const float wv0 = wp0 / wsum, wv1 = wp1 / wsum;
    wf[t]         = wv0;
    wf[t + 256]   = wv1;
    outb[t]       = wv0;
    outb[t + 256] = wv1;
    __syncthreads();   // wf rows cross waves now (wave reads 128-row slab)

    // ---- phase 2: new_mem + r ----
    f4v ev[4], av[4], acc[4];
#pragma unroll
    for (int mc = 0; mc < 4; ++mc) {
        ev[mc]  = *reinterpret_cast<const f4v*>(&ea_lds[mc * 64 + sl * 4]);
        av[mc]  = *reinterpret_cast<const f4v*>(&ea_lds[MM + mc * 64 + sl * 4]);
        acc[mc] = (f4v)0.f;
    }
    float* __restrict__ ob0 = outb + (NN + MM) + (size_t)rowbase * MM + sl * 4;

    // issue first two streaming re-reads early (latency hides under reg stores)
    f4v s0b[4], s1b[4];
    ldgrp(s0b, rp0 + (size_t)(4 * (G_REG + 0)) * MM);
    ldgrp(s1b, rp0 + (size_t)(4 * (G_REG + 1)) * MM);

    // register-resident groups: pure compute + NT store
#pragma unroll
    for (int gp = 0; gp < G_REG; ++gp)
        procgrp(tile[gp], wf[rowbase + 4 * gp], ev, av, acc,
                ob0 + (size_t)(4 * gp) * MM);

    // streaming groups: 2-deep ping-pong re-read (L2/L3) + store
#pragma unroll
    for (int j = 0; j < G_STREAM; ++j) {
        if ((j & 1) == 0) {
            procgrp(s0b, wf[rowbase + 4 * (G_REG + j)], ev, av, acc,
                    ob0 + (size_t)(4 * (G_REG + j)) * MM);
            if (j + 2 < G_STREAM)
                ldgrp(s0b, rp0 + (size_t)(4 * (G_REG + j + 2)) * MM);
        } else {
            procgrp(s1b, wf[rowbase + 4 * (G_REG + j)], ev, av, acc,
                    ob0 + (size_t)(4 * (G_REG + j)) * MM);
            if (j + 2 < G_STREAM)
                ldgrp(s1b, rp0 + (size_t)(4 * (G_REG + j + 2)) * MM);
        }
    }

    // reduce r partials across the 4 sub-rows of the wave
#pragma unroll
    for (int mc = 0; mc < 4; ++mc) {
        acc[mc].x += __shfl_xor(acc[mc].x, 16); acc[mc].y += __shfl_xor(acc[mc].y, 16);
        acc[mc].z += __shfl_xor(acc[mc].z, 16); acc[mc].w += __shfl_xor(acc[mc].w, 16);
        acc[mc].x += __shfl_xor(acc[mc].x, 32); acc[mc].y += __shfl_xor(acc[mc].y, 32);
        acc[mc].z += __shfl_xor(acc[mc].z, 32); acc[mc].w += __shfl_xor(acc[mc].w, 32);
    }
    if (sub == 0) {
#pragma unroll
        for (int mc = 0; mc < 4; ++mc)
            *reinterpret_cast<f4v*>(&rpart[wave][mc * 64 + sl * 4]) = acc[mc];
    }
    __syncthreads();
    outb[NN + t] = rpart[0][t] + rpart[1][t] + rpart[2][t] + rpart[3][t];
}

extern "C" void kernel_launch(void* const* d_in, const int* in_sizes, int n_in,
                              void* d_out, int out_size, void* d_ws, size_t ws_size,
                              hipStream_t stream) {
    const float* memory = (const float*)d_in[0];
    const float* key    = (const float*)d_in[1];
    const float* beta   = (const float*)d_in[2];
    const float* g      = (const float*)d_in[3];
    const float* s      = (const float*)d_in[4];
    const float* gamma  = (const float*)d_in[5];
    const float* w_prev = (const float*)d_in[6];
    const float* e      = (const float*)d_in[7];
    const float* a      = (const float*)d_in[8];
    float* out = (float*)d_out;

    ntm_memory_kernel<<<BB, 256, 0, stream>>>(memory, key, beta, g, s, gamma,
                                              w_prev, e, a, out);
}